// Round 9
// baseline (256.755 us; speedup 1.0000x reference)
//
#include <hip/hip_runtime.h>
#include <math.h>

#define BB 2048
#define NN 8192
#define HH 10
#define BETA 0.1f
#define QELEM 2048                    // elements per quantum (256 thr * 8)
#define NQ 4                          // quanta per row

// Hardware transcendentals: v_log_f32 = log2(x), v_exp_f32 = 2^x (~1 ulp each).
// Valid: x = yn - y[k] > 0 for active k (y strictly increasing cumsum of positives).
__device__ __forceinline__ float fast_log2(float x) {
    float r; asm("v_log_f32 %0, %1" : "=v"(r) : "v"(x)); return r;
}
__device__ __forceinline__ float fast_exp2(float x) {
    float r; asm("v_exp_f32 %0, %1" : "=v"(r) : "v"(x)); return r;
}

__device__ __forceinline__ float alpha_of(float yp,
    const float* __restrict__ aw1, const float* __restrict__ ab1,
    const float* __restrict__ aw2, const float* __restrict__ ab2) {
    float m = ab2[0];
    #pragma unroll
    for (int h = 0; h < HH; ++h)
        m += fmaxf(fmaf(yp, aw1[h], ab1[h]), 0.f) * aw2[h];
    const float g   = 1.f - expf(-BETA * yp);
    const float sig = 1.f / (1.f + expf(-m));
    return 1.f - sig * g;
}

__device__ __forceinline__ void finalize_row(
    int b, int n, float a, float t, double sm, double tr,
    const float* __restrict__ yr, const float* __restrict__ dr,
    const float* __restrict__ w1, const float* __restrict__ b1,
    const float* __restrict__ w2, const float* __restrict__ b2,
    float* __restrict__ out)
{
    float dres;
    if (a == 0.f) {
        dres = (float)tr;
    } else if (a == 1.f) {
        dres = dr[n];
    } else if (n == 0) {
        dres = 0.f;
    } else {
        float last = powf(yr[n] - yr[n - 1], t) * dr[n - 1];  // once per row: exact powf
        float fac  = expf(-lgammaf(2.f - a));
        dres = fac * ((float)sm + last);
    }
    float o = b2[0];
    #pragma unroll
    for (int h = 0; h < HH; ++h)
        o += fmaxf(fmaf(dres, w1[h], b1[h]), 0.f) * w2[h];
    out[b] = o;
}

// Grid 8192 = (row b = blk>>2, quantum s = blk&3); 256 threads, 8 elems/thread.
// Every active quantum is a dense 2048-element stream (uniform cost -> CU byte
// balance); inactive quanta exit immediately (backfill). Combine: fp64 atomicAdd
// partials + release fence + counter; the LAST block of each row finalizes.
// No spinning. ws: double sm[BB] | double tr[BB] | int cnt[BB], zeroed per call.
__global__ __launch_bounds__(256) void frac_quantum_kernel(
    const float* __restrict__ y_plus,
    const int*   __restrict__ iidx,
    const float* __restrict__ DU,
    const float* __restrict__ Y,
    const float* __restrict__ aw1, const float* __restrict__ ab1,
    const float* __restrict__ aw2, const float* __restrict__ ab2,
    const float* __restrict__ w1,  const float* __restrict__ b1,
    const float* __restrict__ w2,  const float* __restrict__ b2,
    double* __restrict__ ws_sm, double* __restrict__ ws_tr,
    int*    __restrict__ ws_cnt,
    float*  __restrict__ out)
{
    const int blk = blockIdx.x;
    const int b   = blk >> 2;
    const int s   = blk & 3;
    const int tid = threadIdx.x;
    const int n   = iidx[b];

    const float a = alpha_of(y_plus[b], aw1, ab1, aw2, ab2);
    const float t = 1.f - a;

    // mode & span (block-uniform): main sums k in [0, n-2]; trap k in [0, n-1]
    const bool is_main = (a != 0.f) && (a != 1.f) && (n >= 2);
    const bool is_trap = (a == 0.f) && (n >= 1);
    const int  kend    = is_main ? (n - 2) : (is_trap ? (n - 1) : -1);
    const int  P       = (kend < 0) ? 1 : ((kend + 1 + QELEM - 1) / QELEM >= 1
                                           ? (kend + 1 + QELEM - 1) / QELEM : 1);
    if (s >= P) return;                       // inactive quantum: retire, backfill

    const float* yr = Y  + (size_t)b * NN;
    const float* dr = DU + (size_t)b * NN;

    float sm = 0.f, tr = 0.f;
    if (kend >= 0) {
        const int k0 = s * QELEM + tid * 8;
        if (k0 <= kend) {
            float4 ya = *reinterpret_cast<const float4*>(yr + k0);
            float4 yb = *reinterpret_cast<const float4*>(yr + k0 + 4);
            float4 da = *reinterpret_cast<const float4*>(dr + k0);
            float4 db = *reinterpret_cast<const float4*>(dr + k0 + 4);
            // in-row clamp: value needed only when k0+8 <= kend+1 <= 8191
            const int knext = min(k0 + 8, NN - 1);
            float ynext = yr[knext];
            if (is_main) {
                const float yn = yr[n];
                float yv[9] = {ya.x, ya.y, ya.z, ya.w, yb.x, yb.y, yb.z, yb.w, ynext};
                float dv[8] = {da.x, da.y, da.z, da.w, db.x, db.y, db.z, db.w};
                float p[9];
                #pragma unroll
                for (int j = 0; j < 9; ++j) {
                    float x = fmaxf(yn - yv[j], 1e-30f);
                    p[j] = fast_exp2(t * fast_log2(x));   // telescoped
                }
                #pragma unroll
                for (int q = 0; q < 8; ++q) {
                    float term = (k0 + q <= kend) ? dv[q] : 0.f;
                    sm = fmaf(p[q] - p[q + 1], term, sm);
                }
            } else {                                       // trapezoid
                float dnext = dr[knext];
                float yv[9] = {ya.x, ya.y, ya.z, ya.w, yb.x, yb.y, yb.z, yb.w, ynext};
                float dv[9] = {da.x, da.y, da.z, da.w, db.x, db.y, db.z, db.w, dnext};
                #pragma unroll
                for (int q = 0; q < 8; ++q) {
                    float seg = (yv[q + 1] - yv[q]) * (dv[q + 1] + dv[q]) * 0.5f;
                    tr += (k0 + q <= kend) ? seg : 0.f;
                }
            }
        }
    }

    // block reduce (4 waves)
    double smd = (double)sm, trd = (double)tr;
    for (int off = 32; off > 0; off >>= 1) {
        smd += __shfl_down(smd, off, 64);
        trd += __shfl_down(trd, off, 64);
    }
    __shared__ double s_sm[4], s_tr[4];
    const int wave = tid >> 6, lane = tid & 63;
    if (lane == 0) { s_sm[wave] = smd; s_tr[wave] = trd; }
    __syncthreads();

    if (tid == 0) {
        double smT = s_sm[0] + s_sm[1] + s_sm[2] + s_sm[3];
        double trT = s_tr[0] + s_tr[1] + s_tr[2] + s_tr[3];
        if (P == 1) {
            // single-quantum row: finalize directly, no atomics/workspace
            finalize_row(b, n, a, t, smT, trT, yr, dr, w1, b1, w2, b2, out);
        } else {
            atomicAdd(&ws_sm[b], smT);
            atomicAdd(&ws_tr[b], trT);
            __threadfence();                              // release partials
            int old = atomicAdd(&ws_cnt[b], 1);
            if (old == P - 1) {                           // I'm last: combine + epilogue
                __threadfence();                          // acquire partials
                double smA = atomicAdd(&ws_sm[b], 0.0);   // atomic read
                double trA = atomicAdd(&ws_tr[b], 0.0);
                finalize_row(b, n, a, t, smA, trA, yr, dr, w1, b1, w2, b2, out);
            }
        }
    }
}

extern "C" void kernel_launch(void* const* d_in, const int* in_sizes, int n_in,
                              void* d_out, int out_size, void* d_ws, size_t ws_size,
                              hipStream_t stream) {
    const float* y_plus = (const float*)d_in[0];
    const int*   iidx   = (const int*)  d_in[1];
    const float* DU     = (const float*)d_in[2];
    const float* Y      = (const float*)d_in[3];
    const float* aw1    = (const float*)d_in[4];
    const float* ab1    = (const float*)d_in[5];
    const float* aw2    = (const float*)d_in[6];
    const float* ab2    = (const float*)d_in[7];
    const float* w1     = (const float*)d_in[8];
    const float* b1     = (const float*)d_in[9];
    const float* w2     = (const float*)d_in[10];
    const float* b2     = (const float*)d_in[11];
    float* out = (float*)d_out;

    double* ws_sm  = (double*)d_ws;                 // [BB]
    double* ws_tr  = ws_sm + BB;                    // [BB]
    int*    ws_cnt = (int*)(ws_tr + BB);            // [BB]

    // zero partials + counters (graph-capturable async memset): 2048*(8+8+4) = 40KB
    hipMemsetAsync(d_ws, 0, BB * (sizeof(double) * 2 + sizeof(int)), stream);

    frac_quantum_kernel<<<BB * NQ, 256, 0, stream>>>(
        y_plus, iidx, DU, Y, aw1, ab1, aw2, ab2, w1, b1, w2, b2,
        ws_sm, ws_tr, ws_cnt, out);
}